// Round 5
// baseline (19872.636 us; speedup 1.0000x reference)
//
#include <hip/hip_runtime.h>
#include <hip/hip_bf16.h>
#include <string.h>

typedef __hip_bfloat16 bf16;

__device__ __forceinline__ float b2f(bf16 v){ return __bfloat162float(v); }
__device__ __forceinline__ bf16  f2b(float v){ return __float2bfloat16(v); }
__device__ __forceinline__ float ldf(const float* p, size_t i){ return p[i]; }
__device__ __forceinline__ float ldf(const bf16*  p, size_t i){ return b2f(p[i]); }
__device__ __forceinline__ void stf(float* p, size_t i, float v){ p[i] = v; }
__device__ __forceinline__ void stf(bf16*  p, size_t i, float v){ p[i] = f2b(v); }

// ------------------------------------------------------------------
// block-wide (256 thr) mean/var helper. sred must be float[4] shared.
// ------------------------------------------------------------------
__device__ __forceinline__ float2 block_stats256(float x, float* sred){
  float v = x;
  #pragma unroll
  for (int o = 32; o; o >>= 1) v += __shfl_xor(v, o);
  int w = threadIdx.x >> 6;
  if ((threadIdx.x & 63) == 0) sred[w] = v;
  __syncthreads();
  float mean = (sred[0] + sred[1] + sred[2] + sred[3]) * (1.f/256.f);
  __syncthreads();
  float d = x - mean;
  v = d * d;
  #pragma unroll
  for (int o = 32; o; o >>= 1) v += __shfl_xor(v, o);
  if ((threadIdx.x & 63) == 0) sred[w] = v;
  __syncthreads();
  float var = (sred[0] + sred[1] + sred[2] + sred[3]) * (1.f/256.f);
  __syncthreads();
  return make_float2(mean, var);
}

// ---- diagnostics ----
__global__ __launch_bounds__(256) void probe_k(const bf16* __restrict__ buf,
                                               unsigned long long len, float* score){
  __shared__ float sred[4];
  unsigned long long stride = len / 256ull; if (!stride) stride = 1;
  unsigned long long i = (unsigned long long)threadIdx.x * stride;
  if (i >= len) i = len - 1;
  float v = fabsf(b2f(buf[i]));
  #pragma unroll
  for (int o = 32; o; o >>= 1) v = fmaxf(v, __shfl_xor(v, o));
  if ((threadIdx.x & 63) == 0) sred[threadIdx.x >> 6] = v;
  __syncthreads();
  if (threadIdx.x == 0)
    score[0] = fmaxf(fmaxf(sred[0], sred[1]), fmaxf(sred[2], sred[3]));
}

__global__ void verdict_k(const float* score, int nstage, float* out){
  if (threadIdx.x == 0 && blockIdx.x == 0){
    for (int i = 0; i < nstage; i++){
      float s = score[i];
      if (!(s > 1e-8f)){
        float sent = 1000.f + 40.f * i;
        for (int j = 0; j < 64; j++) out[j] = sent;
        return;
      }
    }
  }
}

// ------------------------------------------------------------------
// Generic GEMM: C[M,N] = act(A[M,K] @ W[N,K]^T + bias[N])
// ------------------------------------------------------------------
template<int ACT, typename TA>
__global__ __launch_bounds__(256) void gemm_nt_k(
    const TA* __restrict__ A, const float* __restrict__ W,
    const float* __restrict__ bias, bf16* __restrict__ C,
    int M, int N, int K)
{
  __shared__ __align__(16) float As[32][68];
  __shared__ __align__(16) float Bs[32][68];
  int t  = threadIdx.x;
  int m0 = blockIdx.y * 64, n0 = blockIdx.x * 64;
  int lk = t & 31;
  int lg = t >> 5;
  int px = (t & 15) * 4;
  int cq = (t >> 4) * 4;
  float acc[4][4] = {};
  #pragma unroll 1
  for (int kk = 0; kk < K; kk += 32) {
    const TA*    ap = A + (size_t)(m0 + lg*8) * K + kk + lk;
    const float* wp = W + (size_t)(n0 + lg*8) * K + kk + lk;
    #pragma unroll
    for (int j = 0; j < 8; j++) As[lk][lg*8+j] = ldf(ap, (size_t)j*K);
    #pragma unroll
    for (int j = 0; j < 8; j++) Bs[lk][lg*8+j] = wp[(size_t)j*K];
    __syncthreads();
    #pragma unroll
    for (int k = 0; k < 32; k++){
      float4 av = *reinterpret_cast<const float4*>(&As[k][px]);
      float4 bv = *reinterpret_cast<const float4*>(&Bs[k][cq]);
      float a[4] = {av.x, av.y, av.z, av.w};
      float b[4] = {bv.x, bv.y, bv.z, bv.w};
      #pragma unroll
      for (int i = 0; i < 4; i++)
        #pragma unroll
        for (int j = 0; j < 4; j++)
          acc[i][j] = fmaf(a[i], b[j], acc[i][j]);
    }
    __syncthreads();
  }
  #pragma unroll
  for (int i = 0; i < 4; i++){
    size_t m = (size_t)(m0 + px + i);
    #pragma unroll
    for (int j = 0; j < 4; j++){
      int nn = n0 + cq + j;
      float v = acc[i][j];
      if (bias) v += bias[nn];
      if (ACT == 1) v = fmaxf(v, 0.f);
      if (ACT == 2) v = v > 0.f ? v : (__expf(v) - 1.f);
      C[m * N + nn] = f2b(v);
    }
  }
}

// ------------------------------------------------------------------
// 3x3 conv, Cin=Cout=256, pad 1, implicit GEMM + fusions.
// ------------------------------------------------------------------
template<int UP2, int STRIDE, int HAS_BN, int RELU, int HAS_RES, int TROUT,
         int GATE, int WOUT, typename TIN, typename TRES, typename TOUT>
__global__ __launch_bounds__(256) void conv3x3_k(
    const TIN* __restrict__ in, int Hi, int Wi,
    const float* __restrict__ w, const float* __restrict__ cbias,
    const float* __restrict__ bng, const float* __restrict__ bnb,
    const TRES* __restrict__ res, bf16* __restrict__ gate,
    TOUT* __restrict__ out, int Ho, int Wo)
{
  __shared__ __align__(16) float As[32][68];
  __shared__ __align__(16) float Bs[32][68];
  const int HW_ = Ho * Wo;
  int n   = blockIdx.z;
  int co0 = blockIdx.y * 64;
  int p0  = blockIdx.x * 64;
  int t   = threadIdx.x;
  int lk  = t & 31;
  int lg  = t >> 5;
  int px  = (t & 15) * 4;
  int cq  = (t >> 4) * 4;

  int oy[8], ox[8]; bool pv[8];
  #pragma unroll
  for (int j = 0; j < 8; j++){
    int p = p0 + lg*8 + j;
    pv[j] = (p < HW_);
    int pp = pv[j] ? p : 0;
    oy[j] = pp / Wo; ox[j] = pp % Wo;
  }
  const int Hv = UP2 ? Hi*2 : Hi;
  const int Wv = UP2 ? Wi*2 : Wi;
  float acc[4][4] = {};

  #pragma unroll 1
  for (int ky = 0; ky < 3; ky++)
  #pragma unroll 1
  for (int kx = 0; kx < 3; kx++){
    int soff[8];
    #pragma unroll
    for (int j = 0; j < 8; j++){
      int iy = oy[j]*STRIDE + ky - 1;
      int ix = ox[j]*STRIDE + kx - 1;
      bool v = pv[j] && iy >= 0 && iy < Hv && ix >= 0 && ix < Wv;
      int sy = UP2 ? (iy >> 1) : iy;
      int sx = UP2 ? (ix >> 1) : ix;
      soff[j] = v ? (sy * Wi + sx) : -1;
    }
    const int kidx = ky*3 + kx;
    #pragma unroll 1
    for (int cc = 0; cc < 256; cc += 32){
      int ci = cc + lk;
      const TIN* ip = in + (size_t)(n*256 + ci) * Hi * Wi;
      #pragma unroll
      for (int j = 0; j < 8; j++)
        As[lk][lg*8+j] = (soff[j] >= 0) ? ldf(ip, (size_t)soff[j]) : 0.f;
      const float* wp = w + (size_t)(co0 + lg*8) * 2304 + ci*9 + kidx;
      #pragma unroll
      for (int j = 0; j < 8; j++)
        Bs[lk][lg*8+j] = wp[(size_t)j * 2304];
      __syncthreads();
      #pragma unroll
      for (int k = 0; k < 32; k++){
        float4 av = *reinterpret_cast<const float4*>(&As[k][px]);
        float4 bv = *reinterpret_cast<const float4*>(&Bs[k][cq]);
        float a[4] = {av.x, av.y, av.z, av.w};
        float b[4] = {bv.x, bv.y, bv.z, bv.w};
        #pragma unroll
        for (int i = 0; i < 4; i++)
          #pragma unroll
          for (int j = 0; j < 4; j++)
            acc[i][j] = fmaf(a[i], b[j], acc[i][j]);
      }
      __syncthreads();
    }
  }
  #pragma unroll
  for (int j = 0; j < 4; j++){
    int co = co0 + cq + j;
    float cb = cbias[co];
    float scale = 1.f, shift = cb;
    if (HAS_BN){ float g = bng[co]; scale = g; shift = cb*g + bnb[co]; }
    #pragma unroll
    for (int i = 0; i < 4; i++){
      int p = p0 + px + i;
      if (p < HW_){
        float v = acc[i][j] * scale + shift;
        if (RELU)    v = fmaxf(v, 0.f);
        size_t nchw = (size_t)(n*256 + co) * HW_ + p;
        if (HAS_RES) v += ldf(res, nchw);
        if (GATE){
          float gv = b2f(gate[nchw]);
          gate[nchw] = f2b(gv / (1.f + __expf(-v)));
        }
        if (WOUT){
          if (TROUT) stf(out, ((size_t)n * HW_ + p) * 256 + co, v);
          else       stf(out, nchw, v);
        }
      }
    }
  }
}

// ------------------------------------------------------------------
// MHA (online softmax). qkv rows (b*S+s), cols [q|k|v] each D=NH*DH.
// ------------------------------------------------------------------
template<int S, int NH, int DH>
__global__ __launch_bounds__(64) void attn_k(
    const bf16* __restrict__ qkv, bf16* __restrict__ out)
{
  const int D = NH * DH;
  int b = blockIdx.x / NH, h = blockIdx.x % NH;
  int chunk = blockIdx.y;
  int lane = threadIdx.x;
  __shared__ float ks[S][DH];
  __shared__ float vs[S][DH];
  __shared__ float os[64][DH];
  for (int idx = lane; idx < S*DH; idx += 64){
    int tt = idx / DH, d = idx % DH;
    size_t row = (size_t)(b*S + tt) * (3*D);
    ks[tt][d] = b2f(qkv[row +   D + h*DH + d]);
    vs[tt][d] = b2f(qkv[row + 2*D + h*DH + d]);
  }
  __syncthreads();
  int s = chunk*64 + lane;
  float q[DH];
  const float scale = 1.f / sqrtf((float)DH);
  if (s < S){
    size_t row = (size_t)(b*S + s) * (3*D);
    #pragma unroll
    for (int d = 0; d < DH; d++) q[d] = b2f(qkv[row + h*DH + d]) * scale;
  } else {
    #pragma unroll
    for (int d = 0; d < DH; d++) q[d] = 0.f;
  }
  float o[DH];
  #pragma unroll
  for (int d = 0; d < DH; d++) o[d] = 0.f;
  float m = -1e30f, l = 0.f;
  for (int tt = 0; tt < S; tt++){
    float sc = 0.f;
    #pragma unroll
    for (int d = 0; d < DH; d++) sc = fmaf(q[d], ks[tt][d], sc);
    float mn = fmaxf(m, sc);
    float corr = __expf(m - mn);
    float e = __expf(sc - mn);
    l = l * corr + e;
    #pragma unroll
    for (int d = 0; d < DH; d++) o[d] = fmaf(o[d], corr, e * vs[tt][d]);
    m = mn;
  }
  float inv = 1.f / l;
  #pragma unroll
  for (int d = 0; d < DH; d++) os[lane][d] = o[d] * inv;
  __syncthreads();
  for (int idx = lane; idx < 64*DH; idx += 64){
    int sl = idx / DH, d = idx % DH;
    int ss = chunk*64 + sl;
    if (ss < S) out[(size_t)(b*S + ss) * D + h*DH + d] = f2b(os[sl][d]);
  }
}

// ------------------------------------------------------------------
// out[r,:] = LN(a[r,:]+b[r,:]) * g + bb  (+ PE[r%49,:] if ADD_PE)
// ------------------------------------------------------------------
template<int ADD_PE, typename TA>
__global__ __launch_bounds__(256) void add_ln_k(
    const TA* __restrict__ a, const bf16* __restrict__ bsrc,
    const float* __restrict__ g, const float* __restrict__ bb, bf16* out)
{
  __shared__ float sred[4];
  int r = blockIdx.x, c = threadIdx.x;
  size_t idx = (size_t)r * 256 + c;
  float x = ldf(a, idx) + b2f(bsrc[idx]);
  float2 mv = block_stats256(x, sred);
  float y = (x - mv.x) * rsqrtf(mv.y + 1e-5f) * g[c] + bb[c];
  if (ADD_PE){
    int s = r % 49;
    float freq = __expf((float)(c & ~1) * (-9.210340371976184f / 256.f));
    float ang = (float)s * freq;
    y += (c & 1) ? cosf(ang) : sinf(ang);
  }
  out[idx] = f2b(y);
}

// ------------------------------------------------------------------
// DynamicConv stage 1: f1[n,s,d] = elu(LN_d(sum_c feats[n,s,c]*p1[n,c,d]))
// ------------------------------------------------------------------
__global__ __launch_bounds__(256) void dyn_e1_k(
    const bf16* __restrict__ k2, const bf16* __restrict__ params,
    const float* __restrict__ g, const float* __restrict__ bb,
    bf16* __restrict__ f1)
{
  int n = blockIdx.x;
  int w = threadIdx.x >> 6, d = threadIdx.x & 63;
  const bf16* pp = params + (size_t)n * 32768 + d;
  for (int s = w; s < 49; s += 4){
    const bf16* fp = k2 + (size_t)n * 256 * 49 + s;
    float acc = 0.f;
    #pragma unroll 4
    for (int c = 0; c < 256; c++)
      acc = fmaf(b2f(fp[c*49]), b2f(pp[c*64]), acc);
    float v = acc;
    #pragma unroll
    for (int o = 32; o; o >>= 1) v += __shfl_xor(v, o);
    float mean = v * (1.f/64.f);
    float dd = acc - mean;
    v = dd * dd;
    #pragma unroll
    for (int o = 32; o; o >>= 1) v += __shfl_xor(v, o);
    float var = v * (1.f/64.f);
    float y = dd * rsqrtf(var + 1e-5f) * g[d] + bb[d];
    y = y > 0.f ? y : (__expf(y) - 1.f);
    f1[((size_t)n*49 + s) * 64 + d] = f2b(y);
  }
}

// ------------------------------------------------------------------
// DynamicConv stage 2 + norm2
// ------------------------------------------------------------------
__global__ __launch_bounds__(256) void dyn_e2_k(
    const bf16* __restrict__ k2, const bf16* __restrict__ params,
    const bf16* __restrict__ f1,
    const float* __restrict__ g2, const float* __restrict__ bb2,
    const float* __restrict__ ng, const float* __restrict__ nb,
    bf16* __restrict__ obj0)
{
  __shared__ float sred[4];
  int ns = blockIdx.x; int n = ns / 49, s = ns % 49;
  int c = threadIdx.x;
  const bf16* pp  = params + (size_t)n * 32768 + 16384 + c;
  const bf16* f1p = f1 + (size_t)ns * 64;
  float acc = 0.f;
  #pragma unroll 8
  for (int d = 0; d < 64; d++)
    acc = fmaf(b2f(f1p[d]), b2f(pp[d*256]), acc);
  float2 mv = block_stats256(acc, sred);
  float y = (acc - mv.x) * rsqrtf(mv.y + 1e-5f) * g2[c] + bb2[c];
  y = y > 0.f ? y : (__expf(y) - 1.f);
  float pro2 = b2f(k2[(size_t)(n*256 + c) * 49 + s]) + y;
  float2 mv2 = block_stats256(pro2, sred);
  float y2 = (pro2 - mv2.x) * rsqrtf(mv2.y + 1e-5f) * ng[c] + nb[c];
  obj0[(size_t)ns * 256 + c] = f2b(y2);
}

// ------------------------------------------------------------------
// gate at 7x7: rec7 = k2 * sigmoid(obj); objn = obj in NCHW.
// ------------------------------------------------------------------
__global__ __launch_bounds__(256) void gate7_k(
    const bf16* __restrict__ k2, const bf16* __restrict__ objf,
    bf16* __restrict__ rec7, bf16* __restrict__ objn)
{
  int idx = blockIdx.x * 256 + threadIdx.x;
  if (idx >= 128*256*49) return;
  int s = idx % 49; int c = (idx / 49) & 255; int n = idx / (49*256);
  float ov = b2f(objf[((size_t)n*49 + s) * 256 + c]);
  objn[idx] = f2b(ov);
  float kv = b2f(k2[idx]);
  rec7[idx] = f2b(kv / (1.f + __expf(-ov)));
}

// ==================================================================
extern "C" void kernel_launch(void* const* d_in, const int* in_sizes, int n_in,
                              void* d_out, int out_size, void* d_ws, size_t ws_size,
                              hipStream_t stream)
{
  (void)hipGetLastError();  // clear stale errors

  static float h_sent[64];
  auto send_sentinel = [&](float val){
    for (int i = 0; i < 64; i++) h_sent[i] = val;
    hipMemcpyAsync(d_out, h_sent, 256, hipMemcpyHostToDevice, stream);
  };

  static const int EXP_SIZES[53] = {
    25690112, 32768, 100352, 1179648, 512, 512, 512, 196608, 768, 65536,
    256, 256, 256, 256, 256, 256, 256, 8388608, 32768, 64,
    64, 256, 256, 524288, 2048, 524288, 256, 589824, 2304, 196608,
    768, 768, 768, 768, 768, 1572864, 6144, 1572864, 768, 1179648,
    512, 512, 512, 1179648, 512, 512, 512, 1179648, 512, 589824,
    256, 256, 256 };
  if (n_in != 53){ send_sentinel(6600.f + (float)n_in); return; }
  for (int i = 0; i < 53; i++)
    if (in_sizes[i] != EXP_SIZES[i]){ send_sentinel(6000.f + 10.f*i); return; }
  if (out_size != 25690112){ send_sentinel(3000.f + (float)(out_size >> 20)); return; }
  if (ws_size < 77070400ull){ send_sentinel(2000.f + (float)(ws_size >> 20)); return; }

  // Inputs fp32 (reference dtype); OUTPUT fp32 as well.
  const float* roi    = (const float*)d_in[0];
  const float* proF   = (const float*)d_in[1];
  const float* encW   = (const float*)d_in[3];
  const float* encB   = (const float*)d_in[4];
  const float* encG   = (const float*)d_in[5];
  const float* encBB  = (const float*)d_in[6];
  const float* aqkvW  = (const float*)d_in[7];
  const float* aqkvB  = (const float*)d_in[8];
  const float* aoutW  = (const float*)d_in[9];
  const float* aoutB  = (const float*)d_in[10];
  const float* n1g    = (const float*)d_in[11];
  const float* n1b    = (const float*)d_in[12];
  const float* n2g    = (const float*)d_in[13];
  const float* n2b    = (const float*)d_in[14];
  const float* n3g    = (const float*)d_in[15];
  const float* n3b    = (const float*)d_in[16];
  const float* dynW   = (const float*)d_in[17];
  const float* dynB   = (const float*)d_in[18];
  const float* dn1g   = (const float*)d_in[19];
  const float* dn1b   = (const float*)d_in[20];
  const float* dn2g   = (const float*)d_in[21];
  const float* dn2b   = (const float*)d_in[22];
  const float* lin1W  = (const float*)d_in[23];
  const float* lin1B  = (const float*)d_in[24];
  const float* lin2W  = (const float*)d_in[25];
  const float* lin2B  = (const float*)d_in[26];
  const float* teqkvW = (const float*)d_in[27];
  const float* teqkvB = (const float*)d_in[28];
  const float* teoutW = (const float*)d_in[29];
  const float* teoutB = (const float*)d_in[30];
  const float* teln1g = (const float*)d_in[31];
  const float* teln1b = (const float*)d_in[32];
  const float* teln2g = (const float*)d_in[33];
  const float* teln2b = (const float*)d_in[34];
  const float* teff1W = (const float*)d_in[35];
  const float* teff1B = (const float*)d_in[36];
  const float* teff2W = (const float*)d_in[37];
  const float* teff2B = (const float*)d_in[38];
  const float* recW   = (const float*)d_in[39];
  const float* recB   = (const float*)d_in[40];
  const float* recG   = (const float*)d_in[41];
  const float* recBB  = (const float*)d_in[42];
  const float* dAW    = (const float*)d_in[43];
  const float* dAB    = (const float*)d_in[44];
  const float* dAG    = (const float*)d_in[45];
  const float* dABB   = (const float*)d_in[46];
  const float* dBW    = (const float*)d_in[47];
  const float* dBB_   = (const float*)d_in[48];
  const float* dfW    = (const float*)d_in[49];
  const float* dfB    = (const float*)d_in[50];
  const float* dfG    = (const float*)d_in[51];
  const float* dfBB   = (const float*)d_in[52];

  // ---- workspace layout (bf16 elems) ----
  bf16* base = (bf16*)d_ws;
  const size_t SZ28 = 25690112;
  bf16* k1    = base + 0;
  bf16* k2    = base + 6422528;
  bf16* hbuf  = base + 8028160;
  bf16* C14   = base + 8028160;
  bf16* qkvT  = base + 20873216;
  bf16* rec7  = base + 20873216;
  bf16* objn  = base + 22478848;
  bf16* B28   = base + 0;
  bf16* params= base + 25690112;
  bf16* obj   = base + 29884416;
  bf16* B14   = base + 25690112;
  bf16* obj0  = base + 32112640;
  bf16* tmp   = base + 33718272;
  bf16* atto  = base + 35323904;
  bf16* f1    = base + 36929536;
  bf16* qkvP  = base + 37330944;
  bf16* attoP = base + 37429248;
  bf16* mhaP  = base + 37462016;
  bf16* proQ  = base + 37494784;
  bf16* A14   = base + 32112640;
  bf16* C28   = (bf16*)d_out;       // bf16 scratch in fp32-sized d_out; dead before final conv
  float* score = (float*)((char*)d_ws + 77070336);  // 15-float scoreboard

  // ---- k_encoder: 28 -> 14 -> 7 ----
  conv3x3_k<0,2,1,1,0,0,0,1,float,float,bf16><<<dim3(4,4,128),256,0,stream>>>(
      roi,28,28, encW, encB, encG, encBB, (const float*)nullptr, nullptr, k1, 14,14);
  probe_k<<<1,256,0,stream>>>(k1, 6422528ull, score+0);
  conv3x3_k<0,2,1,1,0,0,0,1,bf16,float,bf16><<<dim3(1,4,128),256,0,stream>>>(
      k1,14,14, encW+589824, encB+256, encG+256, encBB+256, (const float*)nullptr, nullptr, k2, 7,7);
  probe_k<<<1,256,0,stream>>>(k2, 1605632ull, score+1);

  // ---- self-attention over 128 query tokens ----
  gemm_nt_k<0,float><<<dim3(12,2),256,0,stream>>>(proF, aqkvW, aqkvB, qkvP, 128,768,256);
  probe_k<<<1,256,0,stream>>>(qkvP, 98304ull, score+2);
  attn_k<128,8,32><<<dim3(8,2),64,0,stream>>>(qkvP, attoP);
  gemm_nt_k<0,bf16><<<dim3(4,2),256,0,stream>>>(attoP, aoutW, aoutB, mhaP, 128,256,256);
  add_ln_k<0,float><<<128,256,0,stream>>>(proF, mhaP, n1g, n1b, proQ);
  probe_k<<<1,256,0,stream>>>(proQ, 32768ull, score+3);

  // ---- DynamicConv ----
  gemm_nt_k<0,bf16><<<dim3(512,2),256,0,stream>>>(proQ, dynW, dynB, params, 128,32768,256);
  probe_k<<<1,256,0,stream>>>(params, 4194304ull, score+4);
  dyn_e1_k<<<128,256,0,stream>>>(k2, params, dn1g, dn1b, f1);
  probe_k<<<1,256,0,stream>>>(f1, 401408ull, score+5);
  dyn_e2_k<<<6272,256,0,stream>>>(k2, params, f1, dn2g, dn2b, n2g, n2b, obj0);
  probe_k<<<1,256,0,stream>>>(obj0, 1605632ull, score+6);

  // ---- FFN (ELU) + norm3 + PE ----
  gemm_nt_k<2,bf16><<<dim3(32,98),256,0,stream>>>(obj0, lin1W, lin1B, hbuf, 6272,2048,256);
  gemm_nt_k<0,bf16><<<dim3(4,98),256,0,stream>>>(hbuf, lin2W, lin2B, tmp, 6272,256,2048);
  add_ln_k<1,bf16><<<6272,256,0,stream>>>(obj0, tmp, n3g, n3b, obj);
  probe_k<<<1,256,0,stream>>>(obj, 1605632ull, score+7);

  // ---- 3-layer TransformerEncoder (post-norm, relu, nh=4) ----
  for (int l = 0; l < 3; l++){
    gemm_nt_k<0,bf16><<<dim3(12,98),256,0,stream>>>(
        obj, teqkvW + (size_t)l*196608, teqkvB + l*768, qkvT, 6272,768,256);
    attn_k<49,4,64><<<dim3(512,1),64,0,stream>>>(qkvT, atto);
    gemm_nt_k<0,bf16><<<dim3(4,98),256,0,stream>>>(
        atto, teoutW + (size_t)l*65536, teoutB + l*256, tmp, 6272,256,256);
    add_ln_k<0,bf16><<<6272,256,0,stream>>>(obj, tmp, teln1g + l*256, teln1b + l*256, obj);
    gemm_nt_k<1,bf16><<<dim3(32,98),256,0,stream>>>(
        obj, teff1W + (size_t)l*524288, teff1B + l*2048, hbuf, 6272,2048,256);
    gemm_nt_k<0,bf16><<<dim3(4,98),256,0,stream>>>(
        hbuf, teff2W + (size_t)l*524288, teff2B + l*256, tmp, 6272,256,2048);
    add_ln_k<0,bf16><<<6272,256,0,stream>>>(obj, tmp, teln2g + l*256, teln2b + l*256, obj);
  }
  probe_k<<<1,256,0,stream>>>(obj, 1605632ull, score+8);

  // ---- gated rec/det decoder pyramid ----
  gate7_k<<<6272,256,0,stream>>>(k2, obj, rec7, objn);
  probe_k<<<1,256,0,stream>>>(rec7, 1605632ull, score+9);
  probe_k<<<1,256,0,stream>>>(objn, 1605632ull, score+10);
  // 7 -> 14
  conv3x3_k<1,1,1,1,1,0,0,1,bf16,bf16,bf16><<<dim3(4,4,128),256,0,stream>>>(
      rec7,7,7, recW, recB, recG, recBB, k1, nullptr, B14, 14,14);
  probe_k<<<1,256,0,stream>>>(B14, 6422528ull, score+11);
  conv3x3_k<1,1,1,1,0,0,0,1,bf16,float,bf16><<<dim3(4,4,128),256,0,stream>>>(
      objn,7,7, dAW, dAB, dAG, dABB, (const float*)nullptr, nullptr, C14, 14,14);
  probe_k<<<1,256,0,stream>>>(C14, 6422528ull, score+12);
  conv3x3_k<0,1,0,0,1,0,1,1,bf16,bf16,bf16><<<dim3(4,4,128),256,0,stream>>>(
      C14,14,14, dBW, dBB_, nullptr, nullptr, k1, B14, A14, 14,14);
  probe_k<<<1,256,0,stream>>>(A14, 6422528ull, score+13);
  // 14 -> 28
  conv3x3_k<1,1,1,1,1,0,0,1,bf16,float,bf16><<<dim3(13,4,128),256,0,stream>>>(
      B14,14,14, recW+589824, recB+256, recG+256, recBB+256, roi, nullptr, B28, 28,28);
  probe_k<<<1,256,0,stream>>>(B28, SZ28, score+14);
  conv3x3_k<1,1,1,1,0,0,0,1,bf16,float,bf16><<<dim3(13,4,128),256,0,stream>>>(
      A14,14,14, dAW+589824, dAB+256, dAG+256, dABB+256, (const float*)nullptr, nullptr, C28, 28,28);
  conv3x3_k<0,1,0,0,1,0,1,0,bf16,float,bf16><<<dim3(13,4,128),256,0,stream>>>(
      C28,28,28, dBW+589824, dBB_+256, nullptr, nullptr, roi, B28, nullptr, 28,28);
  // final conv + BN + ReLU, transposed (n, 784, 256), FP32 into d_out
  conv3x3_k<0,1,1,1,0,1,0,1,bf16,float,float><<<dim3(13,4,128),256,0,stream>>>(
      B28,28,28, dfW, dfB, dfG, dfBB, (const float*)nullptr, nullptr, (float*)d_out, 28,28);

  // ---- verdict + launch-error readout ----
  verdict_k<<<1,64,0,stream>>>(score, 15, (float*)d_out);
  hipError_t le = hipGetLastError();
  if (le != hipSuccess){
    float v = 7000.f + 16.f * (float)(int)le;
    if (v > 60000.f) v = 60000.f;
    send_sentinel(v);
  }
}